// Round 1
// baseline (211.409 us; speedup 1.0000x reference)
//
#include <hip/hip_runtime.h>

typedef __bf16 bf16;
typedef __bf16 bf16x8 __attribute__((ext_vector_type(8)));
typedef float f32x4 __attribute__((ext_vector_type(4)));

// Problem constants
#define NB    2048
#define NM    26
#define NK    32
#define NH    128
#define NROWS (NB*NK)   // 65536 rows = (b,k) pairs

// ---------------- prep kernels: fp32 -> bf16 with layout reorder ----------------

// xb32[(b*32+k)*32 + j] = inputs[b][j][k]  (j>=26 -> 0)
__global__ __launch_bounds__(256) void prep_x(const float* __restrict__ in, bf16* __restrict__ xb) {
  int e = blockIdx.x * 256 + threadIdx.x;      // [0, NROWS*32)
  int row = e >> 5, j = e & 31;
  int b = row >> 5, k = row & 31;
  float v = (j < NM) ? in[b*(NM*NK) + j*NK + k] : 0.f;
  xb[e] = (bf16)v;
}

// w1r[h][j*32+i] = W1[h][i][j]   (i>=26 -> 0); inner dim 832 = 26*32
__global__ __launch_bounds__(256) void prep_w1(const float* __restrict__ w, bf16* __restrict__ wr) {
  int e = blockIdx.x * 256 + threadIdx.x;      // [0, 128*832)
  int h = e / 832, r = e - h*832;
  int j = r >> 5, i = r & 31;
  float v = (i < NM) ? w[h*(NM*NM) + i*NM + j] : 0.f;
  wr[e] = (bf16)v;
}

// w2r[h][j*128+i] = W2[h][i][j]; inner dim 3328 = 26*128
__global__ __launch_bounds__(256) void prep_w2(const float* __restrict__ w, bf16* __restrict__ wr) {
  int e = blockIdx.x * 256 + threadIdx.x;      // [0, 128*3328)
  int h = e / 3328, r = e - h*3328;
  int j = r >> 7, i = r & 127;
  wr[e] = (bf16)w[h*(NH*NM) + i*NM + j];
}

// ---------------- layer 1 GEMM: rows=65536, N=128, K_inner=832 ----------------
// A[row][c*32+i] = xb[row][c] * xb[row][i]   (chunk c == j index)
__global__ __launch_bounds__(256) void cin1(
    const bf16* __restrict__ xb, const bf16* __restrict__ w1r,
    const float* __restrict__ b1, bf16* __restrict__ x1b)
{
  __shared__ __align__(16) bf16 ldsX[128*32];
  __shared__ __align__(16) bf16 ldsA[128*32];
  __shared__ __align__(16) bf16 ldsB[128*32];
  const int t = threadIdx.x;
  const int rowBase = blockIdx.x * 128;

  { // stage X tile (contiguous 8 KB)
    const uint4* s = (const uint4*)(xb + rowBase*32);
    uint4* d = (uint4*)ldsX;
    d[t] = s[t]; d[t+256] = s[t+256];
  }

  const int lane = t & 63, w = t >> 6;
  const int rs = (w >> 1)*64, cs = (w & 1)*64;
  const int lr = lane & 15, lq = lane >> 4;
  const int arow = t >> 1, ac0 = (t & 1)*16;

  f32x4 acc[4][4];
  #pragma unroll
  for (int mi=0; mi<4; ++mi)
    #pragma unroll
    for (int ni=0; ni<4; ++ni) acc[mi][ni] = {0.f,0.f,0.f,0.f};

  for (int c = 0; c < 26; ++c) {
    __syncthreads();
    // stage B chunk: ldsB[h][kk] = w1r[h][c*32+kk]
    #pragma unroll
    for (int p = 0; p < 2; ++p) {
      int tt = p*256 + t; int h = tt >> 2; int ko = (tt & 3)*8;
      *(uint4*)&ldsB[h*32 + ko] = *(const uint4*)&w1r[h*832 + c*32 + ko];
    }
    // build A chunk: A[row][i] = X[row][c] * X[row][i]
    float sc = (float)ldsX[arow*32 + c];
    #pragma unroll
    for (int g = 0; g < 2; ++g) {
      bf16x8 xv = *(const bf16x8*)&ldsX[arow*32 + ac0 + g*8];
      bf16x8 av;
      #pragma unroll
      for (int e2 = 0; e2 < 8; ++e2) av[e2] = (bf16)(sc * (float)xv[e2]);
      *(bf16x8*)&ldsA[arow*32 + ac0 + g*8] = av;
    }
    __syncthreads();
    bf16x8 af[4], bfr[4];
    #pragma unroll
    for (int mi=0; mi<4; ++mi) af[mi]  = *(const bf16x8*)&ldsA[(rs+mi*16+lr)*32 + lq*8];
    #pragma unroll
    for (int ni=0; ni<4; ++ni) bfr[ni] = *(const bf16x8*)&ldsB[(cs+ni*16+lr)*32 + lq*8];
    #pragma unroll
    for (int mi=0; mi<4; ++mi)
      #pragma unroll
      for (int ni=0; ni<4; ++ni)
        acc[mi][ni] = __builtin_amdgcn_mfma_f32_16x16x32_bf16(af[mi], bfr[ni], acc[mi][ni], 0, 0, 0);
  }

  // epilogue: +bias, store bf16
  float bias[4];
  #pragma unroll
  for (int ni=0; ni<4; ++ni) bias[ni] = b1[cs + ni*16 + lr];
  #pragma unroll
  for (int mi=0; mi<4; ++mi)
    #pragma unroll
    for (int ni=0; ni<4; ++ni) {
      int col = cs + ni*16 + lr;
      #pragma unroll
      for (int r=0; r<4; ++r) {
        int row = rowBase + rs + mi*16 + lq*4 + r;
        x1b[row*128 + col] = (bf16)(acc[mi][ni][r] + bias[ni]);
      }
    }
}

// ---------------- layer 2 GEMM: rows=65536, N=128, K_inner=3328 ----------------
// chunk c: j = c>>2, i0 = (c&3)*32;  A[row][kk] = xb[row][j] * x1[row][i0+kk]
__global__ __launch_bounds__(256) void cin2(
    const bf16* __restrict__ xb, const bf16* __restrict__ x1b,
    const bf16* __restrict__ w2r, const float* __restrict__ b2,
    bf16* __restrict__ x2b)
{
  __shared__ __align__(16) bf16 ldsX1[128*128];
  __shared__ __align__(16) bf16 ldsXb[128*32];
  __shared__ __align__(16) bf16 ldsA[128*32];
  __shared__ __align__(16) bf16 ldsB[128*32];
  const int t = threadIdx.x;
  const int rowBase = blockIdx.x * 128;

  {
    const uint4* s = (const uint4*)(x1b + rowBase*128);
    uint4* d = (uint4*)ldsX1;
    #pragma unroll
    for (int p = 0; p < 8; ++p) d[p*256 + t] = s[p*256 + t];
    const uint4* s2 = (const uint4*)(xb + rowBase*32);
    uint4* d2 = (uint4*)ldsXb;
    d2[t] = s2[t]; d2[t+256] = s2[t+256];
  }

  const int lane = t & 63, w = t >> 6;
  const int rs = (w >> 1)*64, cs = (w & 1)*64;
  const int lr = lane & 15, lq = lane >> 4;
  const int arow = t >> 1, ac0 = (t & 1)*16;

  f32x4 acc[4][4];
  #pragma unroll
  for (int mi=0; mi<4; ++mi)
    #pragma unroll
    for (int ni=0; ni<4; ++ni) acc[mi][ni] = {0.f,0.f,0.f,0.f};

  for (int c = 0; c < 104; ++c) {
    const int j = c >> 2, i0 = (c & 3)*32;
    __syncthreads();
    #pragma unroll
    for (int p = 0; p < 2; ++p) {
      int tt = p*256 + t; int h = tt >> 2; int ko = (tt & 3)*8;
      *(uint4*)&ldsB[h*32 + ko] = *(const uint4*)&w2r[h*3328 + c*32 + ko];
    }
    float sc = (float)ldsXb[arow*32 + j];
    #pragma unroll
    for (int g = 0; g < 2; ++g) {
      bf16x8 xv = *(const bf16x8*)&ldsX1[arow*128 + i0 + ac0 + g*8];
      bf16x8 av;
      #pragma unroll
      for (int e2 = 0; e2 < 8; ++e2) av[e2] = (bf16)(sc * (float)xv[e2]);
      *(bf16x8*)&ldsA[arow*32 + ac0 + g*8] = av;
    }
    __syncthreads();
    bf16x8 af[4], bfr[4];
    #pragma unroll
    for (int mi=0; mi<4; ++mi) af[mi]  = *(const bf16x8*)&ldsA[(rs+mi*16+lr)*32 + lq*8];
    #pragma unroll
    for (int ni=0; ni<4; ++ni) bfr[ni] = *(const bf16x8*)&ldsB[(cs+ni*16+lr)*32 + lq*8];
    #pragma unroll
    for (int mi=0; mi<4; ++mi)
      #pragma unroll
      for (int ni=0; ni<4; ++ni)
        acc[mi][ni] = __builtin_amdgcn_mfma_f32_16x16x32_bf16(af[mi], bfr[ni], acc[mi][ni], 0, 0, 0);
  }

  float bias[4];
  #pragma unroll
  for (int ni=0; ni<4; ++ni) bias[ni] = b2[cs + ni*16 + lr];
  #pragma unroll
  for (int mi=0; mi<4; ++mi)
    #pragma unroll
    for (int ni=0; ni<4; ++ni) {
      int col = cs + ni*16 + lr;
      #pragma unroll
      for (int r=0; r<4; ++r) {
        int row = rowBase + rs + mi*16 + lq*4 + r;
        x2b[row*128 + col] = (bf16)(acc[mi][ni][r] + bias[ni]);
      }
    }
}

// ---------------- final k-reduction: out[b][h] = sum_k x[b,h,k] ----------------
__global__ __launch_bounds__(256) void reduce_k(
    const bf16* __restrict__ x1b, const bf16* __restrict__ x2b, float* __restrict__ out)
{
  int b = blockIdx.x, h = threadIdx.x;
  const bf16* src = (h < 128) ? (x1b + b*32*128 + h) : (x2b + b*32*128 + (h - 128));
  float s = 0.f;
  #pragma unroll
  for (int k = 0; k < 32; ++k) s += (float)src[k*128];
  out[b*256 + h] = s;
}

// ---------------- launch ----------------
extern "C" void kernel_launch(void* const* d_in, const int* in_sizes, int n_in,
                              void* d_out, int out_size, void* d_ws, size_t ws_size,
                              hipStream_t stream) {
  const float* in = (const float*)d_in[0];
  const float* W1 = (const float*)d_in[1];
  const float* b1 = (const float*)d_in[2];
  const float* W2 = (const float*)d_in[3];
  const float* b2 = (const float*)d_in[4];
  float* out = (float*)d_out;

  char* ws = (char*)d_ws;
  bf16* xb  = (bf16*)(ws);               // 65536*32*2  = 4   MiB
  bf16* w1r = (bf16*)(ws + 4194304);     // 128*832*2   = 208 KiB
  bf16* w2r = (bf16*)(ws + 4407296);     // 128*3328*2  = 832 KiB
  bf16* x1b = (bf16*)(ws + 5259264);     // 65536*128*2 = 16  MiB
  bf16* x2b = (bf16*)(ws + 22036480);    // 16 MiB  (total ~37 MiB)

  prep_x <<<NROWS*32/256, 256, 0, stream>>>(in, xb);
  prep_w1<<<128*832/256,  256, 0, stream>>>(W1, w1r);
  prep_w2<<<128*3328/256, 256, 0, stream>>>(W2, w2r);
  cin1   <<<NROWS/128,    256, 0, stream>>>(xb, w1r, b1, x1b);
  cin2   <<<NROWS/128,    256, 0, stream>>>(xb, x1b, w2r, b2, x2b);
  reduce_k<<<NB,          256, 0, stream>>>(x1b, x2b, out);
}

// Round 2
// 193.087 us; speedup vs baseline: 1.0949x; 1.0949x over previous
//
#include <hip/hip_runtime.h>

typedef __bf16 bf16;
typedef __bf16 bf16x8 __attribute__((ext_vector_type(8)));
typedef float f32x4 __attribute__((ext_vector_type(4)));

#define NB    2048
#define NM    26
#define NK    32
#define NH    128
#define NROWS (NB*NK)   // 65536 rows = (b,k) pairs

__device__ __forceinline__ void gl_lds16(const bf16* g, bf16* l) {
  __builtin_amdgcn_global_load_lds(
      (const __attribute__((address_space(1))) void*)g,
      (__attribute__((address_space(3))) void*)l, 16, 0, 0);
}

// ---------------- prep kernels: fp32 -> bf16 with layout reorder ----------------

// xb[(b*32+k)*32 + j] = inputs[b][j][k]  (j>=26 -> 0)
__global__ __launch_bounds__(256) void prep_x(const float* __restrict__ in, bf16* __restrict__ xb) {
  int e = blockIdx.x * 256 + threadIdx.x;
  int row = e >> 5, j = e & 31;
  int b = row >> 5, k = row & 31;
  float v = (j < NM) ? in[b*(NM*NK) + j*NK + k] : 0.f;
  xb[e] = (bf16)v;
}

// w1r[h][c*32+i] = W1[h][i][c]   (i>=26 -> 0); inner dim 832 = 26*32
__global__ __launch_bounds__(256) void prep_w1(const float* __restrict__ w, bf16* __restrict__ wr) {
  int e = blockIdx.x * 256 + threadIdx.x;
  int h = e / 832, r = e - h*832;
  int j = r >> 5, i = r & 31;
  float v = (i < NM) ? w[h*(NM*NM) + i*NM + j] : 0.f;
  wr[e] = (bf16)v;
}

// w2r[h][j*128+i] = W2[h][i][j]; inner dim 3328 = 26*128
__global__ __launch_bounds__(256) void prep_w2(const float* __restrict__ w, bf16* __restrict__ wr) {
  int e = blockIdx.x * 256 + threadIdx.x;
  int h = e / 3328, r = e - h*3328;
  int j = r >> 7, i = r & 127;
  wr[e] = (bf16)w[h*(NH*NM) + i*NM + j];
}

// ---------------- layer 1: rows=65536, N=128, K=832 (26 chunks of 32) ----------
// A[row][c*32+i] = X[row][c]*X[row][i]; writes x1b (bf16, +bias) and out[:,0:128]
__global__ __launch_bounds__(256, 3) void cin1(
    const bf16* __restrict__ xb, const bf16* __restrict__ w1r,
    const float* __restrict__ b1, bf16* __restrict__ x1b,
    float* __restrict__ out)
{
  __shared__ __align__(16) bf16 ldsXb[128*32];
  __shared__ __align__(16) bf16 ldsA[2][128*32];
  __shared__ __align__(16) bf16 ldsB[2][128*32];
  const int t = threadIdx.x;
  const int rowBase = blockIdx.x * 128;

  { const uint4* s = (const uint4*)(xb + rowBase*32);
    uint4* d = (uint4*)ldsXb; d[t] = s[t]; d[t+256] = s[t+256]; }

  const int lane = t & 63, w = t >> 6;
  const int rs = (w >> 1)*64, cs = (w & 1)*64;
  const int lr = lane & 15, lq = lane >> 4;
  const int arow = t >> 1, ac0 = (t & 1)*16;
  const int h0 = t >> 2, sub = t & 3;

  // x half-row in registers (cols ac0..ac0+16 of padded 32-wide row)
  bf16x8 xr[2];
  #pragma unroll
  for (int g = 0; g < 2; ++g)
    xr[g] = *(const bf16x8*)&xb[(rowBase+arow)*32 + ac0 + g*8];

  f32x4 acc[4][4];
  #pragma unroll
  for (int mi=0; mi<4; ++mi)
    #pragma unroll
    for (int ni=0; ni<4; ++ni) acc[mi][ni] = {0.f,0.f,0.f,0.f};

  __syncthreads();

  int buf = 0;
  for (int c = 0; c < 26; ++c) {
    // async B stage: ldsB[buf][h][kk] = w1r[h][c*32+kk]
    const bf16* bsrc = w1r + c*32;
    gl_lds16(bsrc + h0*832      + sub*8, &ldsB[buf][t*8]);
    gl_lds16(bsrc + (64+h0)*832 + sub*8, &ldsB[buf][2048 + t*8]);
    // A build from registers
    float sc = (float)ldsXb[arow*32 + c];
    #pragma unroll
    for (int g = 0; g < 2; ++g) {
      bf16x8 xv = xr[g]; bf16x8 av;
      #pragma unroll
      for (int e = 0; e < 8; ++e) av[e] = (bf16)(sc * (float)xv[e]);
      *(bf16x8*)&ldsA[buf][arow*32 + ac0 + g*8] = av;
    }
    __syncthreads();
    bf16x8 af[4], bfr[4];
    #pragma unroll
    for (int mi=0; mi<4; ++mi) af[mi]  = *(const bf16x8*)&ldsA[buf][(rs+mi*16+lr)*32 + lq*8];
    #pragma unroll
    for (int ni=0; ni<4; ++ni) bfr[ni] = *(const bf16x8*)&ldsB[buf][(cs+ni*16+lr)*32 + lq*8];
    #pragma unroll
    for (int mi=0; mi<4; ++mi)
      #pragma unroll
      for (int ni=0; ni<4; ++ni)
        acc[mi][ni] = __builtin_amdgcn_mfma_f32_16x16x32_bf16(af[mi], bfr[ni], acc[mi][ni], 0, 0, 0);
    buf ^= 1;
  }

  // epilogue 1: x1b = bf16(acc + bias)
  float bias[4];
  #pragma unroll
  for (int ni=0; ni<4; ++ni) bias[ni] = b1[cs + ni*16 + lr];
  #pragma unroll
  for (int mi=0; mi<4; ++mi)
    #pragma unroll
    for (int ni=0; ni<4; ++ni) {
      int col = cs + ni*16 + lr;
      #pragma unroll
      for (int r=0; r<4; ++r) {
        int row = rowBase + rs + mi*16 + lq*4 + r;
        x1b[row*128 + col] = (bf16)(acc[mi][ni][r] + bias[ni]);
      }
    }
  // epilogue 2: out[b][col] = sum_k x1 = sum(acc) + 32*bias
  const int bBase = rowBase >> 5;
  #pragma unroll
  for (int half=0; half<2; ++half) {
    int b = bBase + (rs >> 5) + half;
    #pragma unroll
    for (int ni=0; ni<4; ++ni) {
      float v = 0.f;
      #pragma unroll
      for (int r=0; r<4; ++r) v += acc[half*2][ni][r] + acc[half*2+1][ni][r];
      v += __shfl_xor(v, 16, 64);
      v += __shfl_xor(v, 32, 64);
      if (lq == 0) {
        int col = cs + ni*16 + lr;
        out[b*256 + col] = v + 32.0f * bias[ni];
      }
    }
  }
}

// ---------------- layer 2: rows=65536, N=128, K=3328 (104 chunks) --------------
// chunk c=(j,ii): A[row][kk] = x0[row][j] * x1[row][ii*32+kk]; x2 never stored:
// out[b][128+col] = sum_k x2 = sum(acc) + 32*b2[col]
__global__ __launch_bounds__(256, 3) void cin2(
    const bf16* __restrict__ xb, const bf16* __restrict__ x1b,
    const bf16* __restrict__ w2r, const float* __restrict__ b2,
    float* __restrict__ out)
{
  __shared__ __align__(16) bf16 ldsXb[128*32];
  __shared__ __align__(16) bf16 ldsA[2][128*32];
  __shared__ __align__(16) bf16 ldsB[2][128*32];
  const int t = threadIdx.x;
  const int rowBase = blockIdx.x * 128;

  { const uint4* s = (const uint4*)(xb + rowBase*32);
    uint4* d = (uint4*)ldsXb; d[t] = s[t]; d[t+256] = s[t+256]; }

  const int lane = t & 63, w = t >> 6;
  const int rs = (w >> 1)*64, cs = (w & 1)*64;
  const int lr = lane & 15, lq = lane >> 4;
  const int arow = t >> 1, ac0 = (t & 1)*16;
  const int h0 = t >> 2, sub = t & 3;

  // x1 half-row in registers: xr[ii][g] = cols ii*32 + ac0 + g*8 ..+8
  bf16x8 xr[4][2];
  #pragma unroll
  for (int ii=0; ii<4; ++ii)
    #pragma unroll
    for (int g=0; g<2; ++g)
      xr[ii][g] = *(const bf16x8*)&x1b[(rowBase+arow)*128 + ii*32 + ac0 + g*8];

  f32x4 acc[4][4];
  #pragma unroll
  for (int mi=0; mi<4; ++mi)
    #pragma unroll
    for (int ni=0; ni<4; ++ni) acc[mi][ni] = {0.f,0.f,0.f,0.f};

  __syncthreads();

  int buf = 0;
  for (int j = 0; j < 26; ++j) {
    float sc = (float)ldsXb[arow*32 + j];
    #pragma unroll
    for (int ii = 0; ii < 4; ++ii) {
      const int c = j*4 + ii;
      const bf16* bsrc = w2r + c*32;
      gl_lds16(bsrc + h0*3328      + sub*8, &ldsB[buf][t*8]);
      gl_lds16(bsrc + (64+h0)*3328 + sub*8, &ldsB[buf][2048 + t*8]);
      #pragma unroll
      for (int g = 0; g < 2; ++g) {
        bf16x8 xv = xr[ii][g]; bf16x8 av;
        #pragma unroll
        for (int e = 0; e < 8; ++e) av[e] = (bf16)(sc * (float)xv[e]);
        *(bf16x8*)&ldsA[buf][arow*32 + ac0 + g*8] = av;
      }
      __syncthreads();
      bf16x8 af[4], bfr[4];
      #pragma unroll
      for (int mi=0; mi<4; ++mi) af[mi]  = *(const bf16x8*)&ldsA[buf][(rs+mi*16+lr)*32 + lq*8];
      #pragma unroll
      for (int ni=0; ni<4; ++ni) bfr[ni] = *(const bf16x8*)&ldsB[buf][(cs+ni*16+lr)*32 + lq*8];
      #pragma unroll
      for (int mi=0; mi<4; ++mi)
        #pragma unroll
        for (int ni=0; ni<4; ++ni)
          acc[mi][ni] = __builtin_amdgcn_mfma_f32_16x16x32_bf16(af[mi], bfr[ni], acc[mi][ni], 0, 0, 0);
      buf ^= 1;
    }
  }

  // epilogue: out[b][128+col] = sum(acc rows of b) + 32*b2[col]
  const int bBase = rowBase >> 5;
  #pragma unroll
  for (int half=0; half<2; ++half) {
    int b = bBase + (rs >> 5) + half;
    #pragma unroll
    for (int ni=0; ni<4; ++ni) {
      float v = 0.f;
      #pragma unroll
      for (int r=0; r<4; ++r) v += acc[half*2][ni][r] + acc[half*2+1][ni][r];
      v += __shfl_xor(v, 16, 64);
      v += __shfl_xor(v, 32, 64);
      if (lq == 0) {
        int col = cs + ni*16 + lr;
        out[b*256 + 128 + col] = v + 32.0f * b2[col];
      }
    }
  }
}

// ---------------- launch ----------------
extern "C" void kernel_launch(void* const* d_in, const int* in_sizes, int n_in,
                              void* d_out, int out_size, void* d_ws, size_t ws_size,
                              hipStream_t stream) {
  const float* in = (const float*)d_in[0];
  const float* W1 = (const float*)d_in[1];
  const float* b1 = (const float*)d_in[2];
  const float* W2 = (const float*)d_in[3];
  const float* b2 = (const float*)d_in[4];
  float* out = (float*)d_out;

  char* ws = (char*)d_ws;
  bf16* xb  = (bf16*)(ws);               // 65536*32*2  = 4   MiB
  bf16* w1r = (bf16*)(ws + 4194304);     // 128*832*2   = 208 KiB
  bf16* w2r = (bf16*)(ws + 4407296);     // 128*3328*2  = 832 KiB
  bf16* x1b = (bf16*)(ws + 5259264);     // 65536*128*2 = 16  MiB

  prep_x <<<NROWS*32/256, 256, 0, stream>>>(in, xb);
  prep_w1<<<128*832/256,  256, 0, stream>>>(W1, w1r);
  prep_w2<<<128*3328/256, 256, 0, stream>>>(W2, w2r);
  cin1   <<<NROWS/128,    256, 0, stream>>>(xb, w1r, b1, x1b, out);
  cin2   <<<NROWS/128,    256, 0, stream>>>(xb, x1b, w2r, b2, out);
}